// Round 2
// baseline (333.144 us; speedup 1.0000x reference)
//
#include <hip/hip_runtime.h>

// LSTM B=4096 T=336 I=21 H=50 OUT=24, fp32 in/out.
// Round 10: move the x-projection OFF the serial h-recurrence path.
//   - Per chunk of CH=8 steps, each wave precomputes xp[tile][s] =
//     scale*(W_ih x(s) + bias) for the NEXT chunk via 2-limb MFMA,
//     accumulated in REGISTERS: the xproj MFMA's D-layout puts lane
//     (q,nl)'s 4 gates of unit 4t+q exactly where the recurrent acc-init
//     needs them (same wave owns the same tiles in both roles) -> no LDS
//     round trip, no fp16 re-round (xp carried f32 across the chunk).
//   - Recurrent step = pure W_hh GEMM, K=64: ONE merged 4-deep MFMA chain
//     per tile (hi,lo limbs into the same f32 acc) initialized from
//     xp[tt][s]. 8 on-path MFMA/wave-step (was 12); no gate adds, no
//     bias movs, no zero-init. xproj-build MFMAs (4-8/wave-step) sit
//     between the chain and the pointwise, filling the MFMA pipe while
//     the other wave on the SIMD runs its trans burst.
//   - xproj-build schedule: chunk c+1's x committed to LDS at end of s=0;
//     slots s'=s-1 built at steps s=1..7 (+ slot 7 at s=7).
//   - Staging tail OOB read fixed (clamped pointer; write still guarded).
//   - Numerics otherwise unchanged (R6/R9): h single fp16 in LDS; weights
//     2 fp16 limbs pre-scaled for exp2 activations; pads compute h=0.
// LDS (halves), conflict-free B-frag reads (const + lane*16B):
//   hbuf[buf2][kb8][col16][8]   : h, k=0..63 (units 0..49 valid, rest 0)
//   xC[buf2][s8][kb4][col16][8] : x, k=0..31 (i<21 valid, rest 0)

#define T_SEQ 336
#define I_IN  21
#define HID   50
#define O_OUT 24
#define MB    16
#define NT    512
#define TPW   2                      // tiles per wave (8 waves -> 16 tiles)
#define CH    8
#define NCH   42                     // 336 / 8
#define XELEM (CH * MB * I_IN)       // 2688 floats per chunk
#define NLD   6                      // ceil(2688 / 512)
#define XBUFH (CH * 4 * 16 * 8)      // 4096 halves per x chunk buffer

#define HIDX(buf, kb, n, j) ((((buf)*8 + (kb))*16 + (n))*8 + (j))
#define XIDX(s, kb, n, j)   ((((s)*4 + (kb))*16 + (n))*8 + (j))

#define K_LOG2E 1.44269504088896340736f

typedef _Float16 f16x8 __attribute__((ext_vector_type(8)));
typedef float    f32x4 __attribute__((ext_vector_type(4)));

#define MFMA16(A, B, C) __builtin_amdgcn_mfma_f32_16x16x32_f16((A), (B), (C), 0, 0, 0)

static __device__ __forceinline__ float frcp(float v) { return __builtin_amdgcn_rcpf(v); }
static __device__ __forceinline__ float ex2(float v)  { return __builtin_amdgcn_exp2f(v); }
// gates pre-scaled: i,f,o by -log2e ; g (and c for tanh) by +2*log2e
static __device__ __forceinline__ float sigm2(float g) { return frcp(1.f + ex2(g)); }
static __device__ __forceinline__ float tanh2(float g) {
    return __builtin_fmaf(-2.f, frcp(1.f + ex2(g)), 1.f);
}

__global__ __launch_bounds__(NT)
void lstm_mfma10(const float* __restrict__ x,
                 const float* __restrict__ W_ih,
                 const float* __restrict__ W_hh,
                 const float* __restrict__ b_ih,
                 const float* __restrict__ b_hh,
                 const float* __restrict__ W_fc,
                 const float* __restrict__ b_fc,
                 float* __restrict__ out)
{
    __shared__ _Float16 hbuf[2 * 8 * 16 * 8];   // 2048 halves = 4 KB
    __shared__ _Float16 xC[2 * XBUFH];          // 8192 halves = 16 KB

    const int tid  = threadIdx.x;
    const int lane = tid & 63;
    const int wv   = tid >> 6;        // 0..7
    const int nl   = lane & 15;       // A: row-in-tile / B: batch col
    const int q    = lane >> 4;       // quad
    const int b0   = blockIdx.x * MB;

    // ---- zero-init LDS (pads must stay 0 forever; h(0)=0) ----
    for (int i = tid; i < 2 * 8 * 16 * 8; i += NT) hbuf[i] = (_Float16)0.f;
    for (int i = tid; i < 2 * XBUFH;      i += NT) xC[i]   = (_Float16)0.f;

    // ---- x staging precompute + issue chunk-0 loads ----
    // element e = tid + k*NT of a chunk: e = ((sI*16)+b)*21 + i
    const float* px[NLD];
    int  xdst[NLD];
    bool xv[NLD];
    float sv[NLD];
    #pragma unroll
    for (int k = 0; k < NLD; ++k) {
        const int e  = tid + k * NT;
        const int i  = e % I_IN;
        const int r  = e / I_IN;
        const int b  = r & 15;
        const int sIr = r >> 4;
        const int sI = (sIr < CH) ? sIr : 0;   // clamp tail (write is guarded)
        xv[k]   = (e < XELEM);
        px[k]   = x + ((size_t)(b0 + b) * T_SEQ + sI) * I_IN + i;
        xdst[k] = XIDX(sI, i >> 3, b, i & 7);
        sv[k]   = px[k][0];            // chunk 0 (overlaps weight build)
    }

    // ---- weights: 2-limb fp16 fragments + bias, built once, pre-scaled ----
    // A[m=nl][k]; packed row p = t*16+nl -> unit=p>>2, gate=p&3
    f16x8 Wh[TPW][2], Wl[TPW][2];   // W_hh, K-chunks 0,1 (k=0..63)
    f16x8 Xh[TPW],    Xl[TPW];      // W_ih, single K-chunk (k=0..31)
    f32x4 biasv[TPW];
    #pragma unroll
    for (int tt = 0; tt < TPW; ++tt) {
        const int t    = wv * TPW + tt;
        const int p    = t * 16 + nl;
        const int unit = p >> 2, gate = p & 3;
        const bool vr  = (unit < HID);
        const float ws = (gate == 2) ? (2.f * K_LOG2E) : (-K_LOG2E);
        const int orig = gate * HID + unit;       // i,f,g,o stacked row
        const int ub   = t * 4 + q;               // unit for D rows q*4+r
        #pragma unroll
        for (int r = 0; r < 4; ++r) {
            const float bs = (r == 2) ? (2.f * K_LOG2E) : (-K_LOG2E);
            biasv[tt][r] = (ub < HID) ? (b_ih[r * HID + ub] + b_hh[r * HID + ub]) * bs : 0.f;
        }
        #pragma unroll
        for (int kc = 0; kc < 2; ++kc) {
            #pragma unroll
            for (int j = 0; j < 8; ++j) {
                const int k = kc * 32 + q * 8 + j;
                const float w = (vr && k < HID) ? W_hh[orig * HID + k] * ws : 0.f;
                const _Float16 hi = (_Float16)w;
                Wh[tt][kc][j] = hi;
                Wl[tt][kc][j] = (_Float16)(w - (float)hi);
            }
        }
        #pragma unroll
        for (int j = 0; j < 8; ++j) {
            const int k = q * 8 + j;
            const float w = (vr && k < I_IN) ? W_ih[orig * I_IN + k] * ws : 0.f;
            const _Float16 hi = (_Float16)w;
            Xh[tt][j] = hi;
            Xl[tt][j] = (_Float16)(w - (float)hi);
        }
    }

    __syncthreads();   // zero-init visible (chunk-0 loads drained by sv use)

    // ---- commit chunk 0 into xC buf 0; advance pointers to chunk 1 ----
    #pragma unroll
    for (int k = 0; k < NLD; ++k) {
        if (xv[k]) xC[xdst[k]] = (_Float16)sv[k];
        px[k] += CH * I_IN;
    }
    __syncthreads();   // chunk-0 x visible

    // pointwise: lane owns units u0,u1 = (2wv+tt)*4+q for batch nl
    const int u0 = (wv * TPW + 0) * 4 + q;
    const int u1 = (wv * TPW + 1) * 4 + q;
    const int hwo0 = ((u0 >> 3) * 16 + nl) * 8 + (u0 & 7);   // + buf*1024
    const int hwo1 = ((u1 >> 3) * 16 + nl) * 8 + (u1 & 7);
    float cst0 = 0.f, cst1 = 0.f;

    const _Float16* hb0 = &hbuf[HIDX(0, q, nl, 0)];
    const int bfo = ((q * 16) + nl) * 8;           // B-frag offset within step

    // ---- xp prologue: xproj+bias for chunk 0, in registers ----
    f32x4 xp[TPW][CH];
    #pragma unroll
    for (int s = 0; s < CH; ++s) {
        const f16x8 XN = *(const f16x8*)&xC[s * 512 + bfo];
        xp[0][s] = MFMA16(Xh[0], XN, biasv[0]);
        xp[0][s] = MFMA16(Xl[0], XN, xp[0][s]);
        xp[1][s] = MFMA16(Xh[1], XN, biasv[1]);
        xp[1][s] = MFMA16(Xl[1], XN, xp[1][s]);
    }

    for (int c = 0; c < NCH; ++c) {
        const int  rb    = (c & 1) * XBUFH;
        const int  wb    = ((c + 1) & 1) * XBUFH;
        const bool dostg = (c + 1) < NCH;
        #pragma unroll
        for (int s = 0; s < CH; ++s) {
            __syncthreads();   // hbuf[cur] (h) complete; xC[rb]/[wb] staged

            // staging loads for next chunk: first thing after the barrier
            if (s == 0 && dostg) {
                #pragma unroll
                for (int k = 0; k < NLD; ++k) sv[k] = px[k][0];
            }

            const int cur = s & 1, nxt = cur ^ 1;

            // ---- h B-frags: 2 contiguous b128 reads ----
            const _Float16* hb = hb0 + cur * 1024;
            const f16x8 B0 = *(const f16x8*)(hb);
            const f16x8 B1 = *(const f16x8*)(hb + 512);

            // ---- recurrent MFMA: 2 merged 4-deep chains, init = xp ----
            f32x4 a0 = xp[0][s];
            f32x4 a1 = xp[1][s];
            a0 = MFMA16(Wh[0][0], B0, a0);
            a1 = MFMA16(Wh[1][0], B0, a1);
            a0 = MFMA16(Wh[0][1], B1, a0);
            a1 = MFMA16(Wh[1][1], B1, a1);
            a0 = MFMA16(Wl[0][0], B0, a0);
            a1 = MFMA16(Wl[1][0], B0, a1);
            a0 = MFMA16(Wl[0][1], B1, a0);
            a1 = MFMA16(Wl[1][1], B1, a1);

            // ---- xproj build for chunk c+1 (off the critical path) ----
            // slot s' = s-1 at steps 1..7, plus slot 7 at step 7.
            if (dostg && s >= 1) {
                const int sp = s - 1;
                const f16x8 XN = *(const f16x8*)&xC[wb + sp * 512 + bfo];
                xp[0][sp] = MFMA16(Xh[0], XN, biasv[0]);
                xp[0][sp] = MFMA16(Xl[0], XN, xp[0][sp]);
                xp[1][sp] = MFMA16(Xh[1], XN, biasv[1]);
                xp[1][sp] = MFMA16(Xl[1], XN, xp[1][sp]);
            }
            if (dostg && s == CH - 1) {
                const int sp = CH - 1;
                const f16x8 XN = *(const f16x8*)&xC[wb + sp * 512 + bfo];
                xp[0][sp] = MFMA16(Xh[0], XN, biasv[0]);
                xp[0][sp] = MFMA16(Xl[0], XN, xp[0][sp]);
                xp[1][sp] = MFMA16(Xh[1], XN, biasv[1]);
                xp[1][sp] = MFMA16(Xl[1], XN, xp[1][sp]);
            }

            // ---- pointwise cell updates, in registers, unguarded ----
            // (pad units: weights+bias 0 -> h computes to exactly 0)
            {
                const float cc = __builtin_fmaf(sigm2(a0[1]), cst0,
                                                sigm2(a0[0]) * tanh2(a0[2]));
                cst0 = cc;
                const float h = sigm2(a0[3]) * tanh2(2.f * K_LOG2E * cc);
                hbuf[nxt * 1024 + hwo0] = (_Float16)h;
            }
            {
                const float cc = __builtin_fmaf(sigm2(a1[1]), cst1,
                                                sigm2(a1[0]) * tanh2(a1[2]));
                cst1 = cc;
                const float h = sigm2(a1[3]) * tanh2(2.f * K_LOG2E * cc);
                hbuf[nxt * 1024 + hwo1] = (_Float16)h;
            }

            // ---- commit staged x(next chunk) into the other x buffer ----
            if (s == 0 && dostg) {
                #pragma unroll
                for (int k = 0; k < NLD; ++k) {
                    if (xv[k]) xC[wb + xdst[k]] = (_Float16)sv[k];
                    px[k] += CH * I_IN;
                }
            }
        }
    }

    __syncthreads();
    // final h: t=335 -> s=7, wrote buf 0
    // ---- FC epilogue: 16*24 = 384 tasks (one-time) ----
    if (tid < MB * O_OUT) {
        const int b = tid / O_OUT, o = tid % O_OUT;
        float a = b_fc[o];
        for (int u = 0; u < HID; ++u) {
            const float hv = (float)hbuf[HIDX(0, u >> 3, b, u & 7)];
            a = __builtin_fmaf(hv, W_fc[o * HID + u], a);
        }
        out[(size_t)(b0 + b) * O_OUT + o] = a;
    }
}

extern "C" void kernel_launch(void* const* d_in, const int* in_sizes, int n_in,
                              void* d_out, int out_size, void* d_ws, size_t ws_size,
                              hipStream_t stream)
{
    const float* x    = (const float*)d_in[0];
    const float* W_ih = (const float*)d_in[1];
    const float* W_hh = (const float*)d_in[2];
    const float* b_ih = (const float*)d_in[3];
    const float* b_hh = (const float*)d_in[4];
    const float* W_fc = (const float*)d_in[5];
    const float* b_fc = (const float*)d_in[6];
    float* out = (float*)d_out;

    lstm_mfma10<<<dim3(4096 / MB), dim3(NT), 0, stream>>>(
        x, W_ih, W_hh, b_ih, b_hh, W_fc, b_fc, out);
}

// Round 3
// 318.865 us; speedup vs baseline: 1.0448x; 1.0448x over previous
//
#include <hip/hip_runtime.h>

// LSTM B=4096 T=336 I=21 H=50 OUT=24, fp32 in/out.
// Round 11: break the 2-waves-per-SIMD phase convoy.
//   R8/R9/R10 showed step time pinned at ~1560 cyc regardless of work
//   redistribution: MFMA busy ~390 cyc/SIMD, VALU+trans ~630, neither ~520,
//   and MFMA+VALU == sum not max -> both waves on a SIMD run MFMA then
//   trans in lockstep. Fix: wave-role phase skew.
//   - Phase group p = (wv ^ (wv>>2)) & 1  (one of each group per SIMD for
//     either wave->SIMD convention): group 0 runs [REC, PW, XP], group 1
//     runs [XP, REC, PW]. XP (~4 indep MFMA) is the phase shifter; pair
//     settles into {A:pointwise || B:MFMA} overlap.
//   - s_setprio(1) around the recurrent MFMA chain (T5: pays only with
//     role diversity, which the skew now provides).
//   - Scaled cell state c~ = 2log2e * c: tanh2 input is c~ directly
//     (saves a mul/cell); update c~' = fma(sigma_f, c~, sigma_i * tg2),
//     tg2 = fma(-2*C2, rcp(1+exp2(gg)), C2) = 2log2e*tanh(g). Exact
//     reparameterization.
//   Carried from R10: xproj off the h-recurrence path (xp[tile][s] in f32
//   regs, built per chunk via 2-limb MFMA with bias as C-init); recurrent
//   step = pure W_hh GEMM K=64, one merged 4-deep chain per tile; x staged
//   per CH=8-step chunk into double-buffered LDS; weights 2 fp16 limbs
//   pre-scaled for exp2 activations; h single fp16 in LDS; pads compute 0.
// LDS (halves), conflict-free B-frag reads (const + lane*16B):
//   hbuf[buf2][kb8][col16][8]   : h, k=0..63 (units 0..49 valid, rest 0)
//   xC[buf2][s8][kb4][col16][8] : x, k=0..31 (i<21 valid, rest 0)

#define T_SEQ 336
#define I_IN  21
#define HID   50
#define O_OUT 24
#define MB    16
#define NT    512
#define TPW   2                      // tiles per wave (8 waves -> 16 tiles)
#define CH    8
#define NCH   42                     // 336 / 8
#define XELEM (CH * MB * I_IN)       // 2688 floats per chunk
#define NLD   6                      // ceil(2688 / 512)
#define XBUFH (CH * 4 * 16 * 8)      // 4096 halves per x chunk buffer

#define HIDX(buf, kb, n, j) ((((buf)*8 + (kb))*16 + (n))*8 + (j))
#define XIDX(s, kb, n, j)   ((((s)*4 + (kb))*16 + (n))*8 + (j))

#define K_LOG2E 1.44269504088896340736f
#define C2SCALE (2.f * K_LOG2E)

typedef _Float16 f16x8 __attribute__((ext_vector_type(8)));
typedef float    f32x4 __attribute__((ext_vector_type(4)));

#define MFMA16(A, B, C) __builtin_amdgcn_mfma_f32_16x16x32_f16((A), (B), (C), 0, 0, 0)

static __device__ __forceinline__ float frcp(float v) { return __builtin_amdgcn_rcpf(v); }
static __device__ __forceinline__ float ex2(float v)  { return __builtin_amdgcn_exp2f(v); }
// gates pre-scaled: i,f,o by -log2e ; g by +2*log2e ; c~ is pre-scaled
static __device__ __forceinline__ float sigm2(float g) { return frcp(1.f + ex2(g)); }
static __device__ __forceinline__ float tanh2(float g) {      // tanh(true arg)
    return __builtin_fmaf(-2.f, frcp(1.f + ex2(g)), 1.f);
}
static __device__ __forceinline__ float tanh2s(float g) {     // 2log2e*tanh(true arg)
    return __builtin_fmaf(-2.f * C2SCALE, frcp(1.f + ex2(g)), C2SCALE);
}

// xproj build for chunk c+1, slot sp (compile-time in unrolled loop)
#define XPROJ(sp)                                                        \
    do {                                                                 \
        const f16x8 XN = *(const f16x8*)&xC[wb + (sp) * 512 + bfo];      \
        xp[0][(sp)] = MFMA16(Xh[0], XN, biasv[0]);                       \
        xp[0][(sp)] = MFMA16(Xl[0], XN, xp[0][(sp)]);                    \
        xp[1][(sp)] = MFMA16(Xh[1], XN, biasv[1]);                       \
        xp[1][(sp)] = MFMA16(Xl[1], XN, xp[1][(sp)]);                    \
    } while (0)

__global__ __launch_bounds__(NT)
void lstm_mfma11(const float* __restrict__ x,
                 const float* __restrict__ W_ih,
                 const float* __restrict__ W_hh,
                 const float* __restrict__ b_ih,
                 const float* __restrict__ b_hh,
                 const float* __restrict__ W_fc,
                 const float* __restrict__ b_fc,
                 float* __restrict__ out)
{
    __shared__ _Float16 hbuf[2 * 8 * 16 * 8];   // 2048 halves = 4 KB
    __shared__ _Float16 xC[2 * XBUFH];          // 8192 halves = 16 KB

    const int tid  = threadIdx.x;
    const int lane = tid & 63;
    const int wv   = tid >> 6;        // 0..7
    const int nl   = lane & 15;       // A: row-in-tile / B: batch col
    const int q    = lane >> 4;       // quad
    const int b0   = blockIdx.x * MB;
    const int ph   = (wv ^ (wv >> 2)) & 1;   // phase group (one of each per SIMD)

    // ---- zero-init LDS (pads must stay 0 forever; h(0)=0) ----
    for (int i = tid; i < 2 * 8 * 16 * 8; i += NT) hbuf[i] = (_Float16)0.f;
    for (int i = tid; i < 2 * XBUFH;      i += NT) xC[i]   = (_Float16)0.f;

    // ---- x staging precompute + issue chunk-0 loads ----
    // element e = tid + k*NT of a chunk: e = ((sI*16)+b)*21 + i
    const float* px[NLD];
    int  xdst[NLD];
    bool xv[NLD];
    float sv[NLD];
    #pragma unroll
    for (int k = 0; k < NLD; ++k) {
        const int e  = tid + k * NT;
        const int i  = e % I_IN;
        const int r  = e / I_IN;
        const int b  = r & 15;
        const int sIr = r >> 4;
        const int sI = (sIr < CH) ? sIr : 0;   // clamp tail (write is guarded)
        xv[k]   = (e < XELEM);
        px[k]   = x + ((size_t)(b0 + b) * T_SEQ + sI) * I_IN + i;
        xdst[k] = XIDX(sI, i >> 3, b, i & 7);
        sv[k]   = px[k][0];            // chunk 0 (overlaps weight build)
    }

    // ---- weights: 2-limb fp16 fragments + bias, built once, pre-scaled ----
    // A[m=nl][k]; packed row p = t*16+nl -> unit=p>>2, gate=p&3
    f16x8 Wh[TPW][2], Wl[TPW][2];   // W_hh, K-chunks 0,1 (k=0..63)
    f16x8 Xh[TPW],    Xl[TPW];      // W_ih, single K-chunk (k=0..31)
    f32x4 biasv[TPW];
    #pragma unroll
    for (int tt = 0; tt < TPW; ++tt) {
        const int t    = wv * TPW + tt;
        const int p    = t * 16 + nl;
        const int unit = p >> 2, gate = p & 3;
        const bool vr  = (unit < HID);
        const float ws = (gate == 2) ? C2SCALE : (-K_LOG2E);
        const int orig = gate * HID + unit;       // i,f,g,o stacked row
        const int ub   = t * 4 + q;               // unit for D rows q*4+r
        #pragma unroll
        for (int r = 0; r < 4; ++r) {
            const float bs = (r == 2) ? C2SCALE : (-K_LOG2E);
            biasv[tt][r] = (ub < HID) ? (b_ih[r * HID + ub] + b_hh[r * HID + ub]) * bs : 0.f;
        }
        #pragma unroll
        for (int kc = 0; kc < 2; ++kc) {
            #pragma unroll
            for (int j = 0; j < 8; ++j) {
                const int k = kc * 32 + q * 8 + j;
                const float w = (vr && k < HID) ? W_hh[orig * HID + k] * ws : 0.f;
                const _Float16 hi = (_Float16)w;
                Wh[tt][kc][j] = hi;
                Wl[tt][kc][j] = (_Float16)(w - (float)hi);
            }
        }
        #pragma unroll
        for (int j = 0; j < 8; ++j) {
            const int k = q * 8 + j;
            const float w = (vr && k < I_IN) ? W_ih[orig * I_IN + k] * ws : 0.f;
            const _Float16 hi = (_Float16)w;
            Xh[tt][j] = hi;
            Xl[tt][j] = (_Float16)(w - (float)hi);
        }
    }

    __syncthreads();   // zero-init visible (chunk-0 loads drained by sv use)

    // ---- commit chunk 0 into xC buf 0; advance pointers to chunk 1 ----
    #pragma unroll
    for (int k = 0; k < NLD; ++k) {
        if (xv[k]) xC[xdst[k]] = (_Float16)sv[k];
        px[k] += CH * I_IN;
    }
    __syncthreads();   // chunk-0 x visible

    // pointwise: lane owns units u0,u1 = (2wv+tt)*4+q for batch nl
    const int u0 = (wv * TPW + 0) * 4 + q;
    const int u1 = (wv * TPW + 1) * 4 + q;
    const int hwo0 = ((u0 >> 3) * 16 + nl) * 8 + (u0 & 7);   // + buf*1024
    const int hwo1 = ((u1 >> 3) * 16 + nl) * 8 + (u1 & 7);
    float cst0 = 0.f, cst1 = 0.f;    // scaled cell state c~ = 2log2e * c

    const _Float16* hb0 = &hbuf[HIDX(0, q, nl, 0)];
    const int bfo = ((q * 16) + nl) * 8;           // B-frag offset within step

    // ---- xp prologue: xproj+bias for chunk 0, in registers ----
    f32x4 xp[TPW][CH];
    {
        const int wb = 0;
        #pragma unroll
        for (int s = 0; s < CH; ++s) XPROJ(s);
    }

    for (int c = 0; c < NCH; ++c) {
        const int  rb    = (c & 1) * XBUFH;
        const int  wb    = ((c + 1) & 1) * XBUFH;
        const bool dostg = (c + 1) < NCH;
        #pragma unroll
        for (int s = 0; s < CH; ++s) {
            __syncthreads();   // hbuf[cur] (h) complete; xC[rb]/[wb] staged

            // staging loads for next chunk: first thing after the barrier
            if (s == 0 && dostg) {
                #pragma unroll
                for (int k = 0; k < NLD; ++k) sv[k] = px[k][0];
            }

            const int cur = s & 1, nxt = cur ^ 1;

            // ---- h B-frags: 2 contiguous b128 reads (critical path) ----
            const _Float16* hb = hb0 + cur * 1024;
            const f16x8 B0 = *(const f16x8*)(hb);
            const f16x8 B1 = *(const f16x8*)(hb + 512);

            // ---- phase group 1: xproj BEFORE recurrent (phase shifter) ----
            if (ph) {
                if (dostg && s >= 1) XPROJ(s - 1);
                if (dostg && s == CH - 1) XPROJ(CH - 1);
            }

            // ---- recurrent MFMA: 2 merged 4-deep chains, init = xp ----
            __builtin_amdgcn_s_setprio(1);
            f32x4 a0 = xp[0][s];
            f32x4 a1 = xp[1][s];
            a0 = MFMA16(Wh[0][0], B0, a0);
            a1 = MFMA16(Wh[1][0], B0, a1);
            a0 = MFMA16(Wh[0][1], B1, a0);
            a1 = MFMA16(Wh[1][1], B1, a1);
            a0 = MFMA16(Wl[0][0], B0, a0);
            a1 = MFMA16(Wl[1][0], B0, a1);
            a0 = MFMA16(Wl[0][1], B1, a0);
            a1 = MFMA16(Wl[1][1], B1, a1);
            __builtin_amdgcn_s_setprio(0);

            // ---- pointwise cell updates, in registers, unguarded ----
            // (pad units: weights+bias 0 -> h computes to exactly 0)
            {
                const float tg2 = tanh2s(a0[2]);
                const float cc  = __builtin_fmaf(sigm2(a0[1]), cst0,
                                                 sigm2(a0[0]) * tg2);
                cst0 = cc;
                const float h = sigm2(a0[3]) * tanh2(cc);
                hbuf[nxt * 1024 + hwo0] = (_Float16)h;
            }
            {
                const float tg2 = tanh2s(a1[2]);
                const float cc  = __builtin_fmaf(sigm2(a1[1]), cst1,
                                                 sigm2(a1[0]) * tg2);
                cst1 = cc;
                const float h = sigm2(a1[3]) * tanh2(cc);
                hbuf[nxt * 1024 + hwo1] = (_Float16)h;
            }

            // ---- phase group 0: xproj AFTER pointwise ----
            if (!ph) {
                if (dostg && s >= 1) XPROJ(s - 1);
                if (dostg && s == CH - 1) XPROJ(CH - 1);
            }

            // ---- commit staged x(next chunk) into the other x buffer ----
            if (s == 0 && dostg) {
                #pragma unroll
                for (int k = 0; k < NLD; ++k) {
                    if (xv[k]) xC[wb + xdst[k]] = (_Float16)sv[k];
                    px[k] += CH * I_IN;
                }
            }
        }
    }

    __syncthreads();
    // final h: t=335 -> s=7, wrote buf 0
    // ---- FC epilogue: 16*24 = 384 tasks (one-time) ----
    if (tid < MB * O_OUT) {
        const int b = tid / O_OUT, o = tid % O_OUT;
        float a = b_fc[o];
        for (int u = 0; u < HID; ++u) {
            const float hv = (float)hbuf[HIDX(0, u >> 3, b, u & 7)];
            a = __builtin_fmaf(hv, W_fc[o * HID + u], a);
        }
        out[(size_t)(b0 + b) * O_OUT + o] = a;
    }
}

extern "C" void kernel_launch(void* const* d_in, const int* in_sizes, int n_in,
                              void* d_out, int out_size, void* d_ws, size_t ws_size,
                              hipStream_t stream)
{
    const float* x    = (const float*)d_in[0];
    const float* W_ih = (const float*)d_in[1];
    const float* W_hh = (const float*)d_in[2];
    const float* b_ih = (const float*)d_in[3];
    const float* b_hh = (const float*)d_in[4];
    const float* W_fc = (const float*)d_in[5];
    const float* b_fc = (const float*)d_in[6];
    float* out = (float*)d_out;

    lstm_mfma11<<<dim3(4096 / MB), dim3(NT), 0, stream>>>(
        x, W_ih, W_hh, b_ih, b_hh, W_fc, b_fc, out);
}